// Round 8
// baseline (40.059 us; speedup 1.0000x reference)
//
#include <hip/hip_runtime.h>
#include <hip/hip_bf16.h>

#define NJ 24
#define TLEN 25000
#define NB 4
#define CHUNKS 7
#define NWPB (CHUNKS*4)            // waves per (b,j) = 28
#define NIT128 ((TLEN+127)/128)    // 196 = 28*7 -> exactly 7 trips/wave

typedef short short8 __attribute__((ext_vector_type(8)));
typedef short s16x2 __attribute__((ext_vector_type(2)));
typedef float f32x16 __attribute__((ext_vector_type(16)));

union FragU { unsigned u[4]; short8 s; };
struct P12 { float v[12]; };

// Fast f32x2 -> packed bf16x2, round-half-up: (bits + 0x8000) then take hi16
// of each via one v_perm_b32. 3 VALU ops. Differs from RTNE only at exact
// half-ulp ties; cannot produce NaN/Inf from finite inputs. NOTE: do NOT use
// inline-asm v_cvt_pk_bf16_f32 — it NaN'd on this toolchain (R5).
__device__ __forceinline__ unsigned pack2(float a, float b){
    unsigned ua = __float_as_uint(a) + 0x8000u;
    unsigned ub = __float_as_uint(b) + 0x8000u;
    return __builtin_amdgcn_perm(ub, ua, 0x07060302u);
}
__device__ __forceinline__ float bflo(unsigned u){
    union { unsigned v; float f; } t; t.v = u << 16; return t.f;
}
// split (a,b) into bf16 hi word + bf16 residual-lo word
__device__ __forceinline__ void split2(float a, float b, unsigned &hi, unsigned &lo){
    unsigned hw = pack2(a, b);
    float fa = bflo(hw);
    union { unsigned v; float f; } th; th.v = hw & 0xffff0000u;
    lo = pack2(a - fa, b - th.f);
    hi = hw;
}

// packed bf16 relu: bf16 bit patterns compare correctly as signed i16;
// max_i16(x, 0) maps any negative bf16 to +0.0 and keeps positives.
__device__ __forceinline__ unsigned pkrelu(unsigned x){
    union { unsigned u; s16x2 v; } a, r;
    a.u = x;
    s16x2 z; z[0] = 0; z[1] = 0;
    r.v = __builtin_elementwise_max(a.v, z);
    return r.u;
}

__device__ __forceinline__ f32x16 mfma(const FragU &a, const FragU &b, f32x16 c){
    return __builtin_amdgcn_mfma_f32_32x32x16_bf16(a.s, b.s, c, 0, 0, 0);
}

__device__ __forceinline__ FragU mk1(unsigned w){
    FragU f; f.u[0] = w; f.u[1] = 0; f.u[2] = 0; f.u[3] = 0; return f;
}

// round-to-bf16 then packed relu (== relu then round); zero-shuffle layer
// chaining: channel labels of next layer are pi-permuted so regs 0..7 -> frag
// k0, 8..15 -> frag k1, compensated in the weight gather below.
__device__ __forceinline__ void relu_pack(const f32x16 &acc, FragU &k0, FragU &k1){
    unsigned w[8];
    #pragma unroll
    for (int i = 0; i < 8; ++i) w[i] = pkrelu(pack2(acc[2*i], acc[2*i+1]));
    k0.u[0]=w[0]; k0.u[1]=w[1]; k0.u[2]=w[2]; k0.u[3]=w[3];
    k1.u[0]=w[4]; k1.u[1]=w[5]; k1.u[2]=w[6]; k1.u[3]=w[7];
}

// launch_bounds(256,2): DO NOT raise the 2nd arg — (256,4) caps the unified
// VGPR/AGPR budget at 128/wave, regalloc split 64+64 and spilled (R2: FETCH
// 303MB / WRITE 184MB scratch traffic, 150us).
// R8: 4 independent 32-col chains per trip (128 cols) — same VALU/col, 4x
// the latency hiding per wave (R3-R7 showed the kernel is chain-latency
// bound, not VALU-issue bound: halving VALU twice moved dur only ~6% each).
__global__ __launch_bounds__(256, 2) void ptf_decoder_kernel(
    const float* __restrict__ p,    const float* __restrict__ c,
    const float* __restrict__ Wproj,const float* __restrict__ bproj,
    const float* __restrict__ Wp,   const float* __restrict__ bp,
    const float* __restrict__ W0,   const float* __restrict__ b0,
    const float* __restrict__ W1,   const float* __restrict__ b1,
    const float* __restrict__ W2,   const float* __restrict__ b2,
    const float* __restrict__ Wout, const float* __restrict__ bout,
    float* __restrict__ out)
{
    __shared__ __align__(16) float ldsW[3][32][36];  // padded: 4-way max on b128 gathers
    __shared__ __align__(16) float ldsWp[32][8];
    __shared__ __align__(16) float ldsB[3][32];
    __shared__ __align__(16) float ldsWo[32];

    const int tid = threadIdx.x;
    const int bj  = blockIdx.x % (NB*NJ);
    const int sub = blockIdx.x / (NB*NJ);
    const int b   = bj / NJ;
    const int j   = bj % NJ;

    // ---- stage this joint's weights into LDS (coalesced) ----
    {
        const float* Wl[3] = {W0, W1, W2};
        #pragma unroll
        for (int L = 0; L < 3; ++L) {
            int row = tid >> 3, c4 = tid & 7;           // 256 threads = 32 rows x 8 float4
            float4 v = *reinterpret_cast<const float4*>(Wl[L] + ((size_t)(j*32 + row))*32 + c4*4);
            *reinterpret_cast<float4*>(&ldsW[L][row][c4*4]) = v;
        }
        {
            int row = tid >> 3, i8 = tid & 7;
            // col 7 carries b_p (first-layer bias rides k=7 with input 1.0)
            ldsWp[row][i8] = (i8 < 7) ? Wp[((size_t)(j*32 + row))*7 + i8]
                                      : bp[j*32 + row];
        }
        if      (tid < 32)  ldsB[0][tid]      = b0[j*32 + tid];
        else if (tid < 64)  ldsB[1][tid-32]   = b1[j*32 + tid-32];
        else if (tid < 96)  ldsB[2][tid-64]   = b2[j*32 + tid-64];
        else if (tid < 128) ldsWo[tid-96]     = Wout[j*32 + tid-96];
    }
    __syncthreads();

    const int lane = tid & 63;
    const int row  = lane & 31;
    const int h    = lane >> 5;

    // ---- per-lane weight fragments (bf16 hi only for hidden layers),
    //      with pi-permuted k labels ----
    FragU whi[3][2];
    #pragma unroll
    for (int L = 0; L < 3; ++L) {
        #pragma unroll
        for (int kh = 0; kh < 2; ++kh) {
            const int g  = kh*2 + h;                 // k-group
            const int cA = (g >> 1)*4 + (g & 1);     // chunk pairs {0,2},{1,3},{4,6},{5,7}
            const float* base = &ldsW[L][row][0];
            float4 x = *reinterpret_cast<const float4*>(base + cA*4);
            float4 y = *reinterpret_cast<const float4*>(base + (cA+2)*4);
            whi[L][kh].u[0] = pack2(x.x, x.y);
            whi[L][kh].u[1] = pack2(x.z, x.w);
            whi[L][kh].u[2] = pack2(y.x, y.y);
            whi[L][kh].u[3] = pack2(y.z, y.w);
        }
    }
    // output layer as MFMA: wo broadcast to all 32 rows, same pi-compensated
    // column gather as whi -> every D reg holds the full 1x32 dot.
    FragU woF[2];
    #pragma unroll
    for (int kh = 0; kh < 2; ++kh) {
        const int g  = kh*2 + h;
        const int cA = (g >> 1)*4 + (g & 1);
        float4 x = *reinterpret_cast<const float4*>(&ldsWo[cA*4]);
        float4 y = *reinterpret_cast<const float4*>(&ldsWo[(cA+2)*4]);
        woF[kh].u[0] = pack2(x.x, x.y);
        woF[kh].u[1] = pack2(x.z, x.w);
        woF[kh].u[2] = pack2(y.x, y.y);
        woF[kh].u[3] = pack2(y.z, y.w);
    }
    FragU wphi, wplo;   // first layer keeps hi+lo weights (true inputs + bias col)
    {
        float4 x = make_float4(0,0,0,0), y = make_float4(0,0,0,0);
        if (lane < 32) {
            x = *reinterpret_cast<const float4*>(&ldsWp[row][0]);
            y = *reinterpret_cast<const float4*>(&ldsWp[row][4]);
        }
        split2(x.x, x.y, wphi.u[0], wplo.u[0]);
        split2(x.z, x.w, wphi.u[1], wplo.u[1]);
        split2(y.x, y.y, wphi.u[2], wplo.u[2]);
        split2(y.z, y.w, wphi.u[3], wplo.u[3]);
    }

    // ---- hidden-layer biases as 1-reg A-fragments: k0=hi(b), k1=lo(b) ----
    unsigned biasA[3];
    #pragma unroll
    for (int L = 0; L < 3; ++L) {
        float bl = (h == 0) ? ldsB[L][row] : 0.f;
        unsigned t = pack2(bl, 0.f);
        float res = bl - bflo(t);
        biasA[L] = (h == 0) ? pack2(bl, res) : 0u;
    }
    const unsigned ones2 = (h == 0) ? 0x3f803f80u : 0u;   // {1.0bf16, 1.0bf16}

    // shared zero accumulator C (read-only)
    f32x16 kZero;
    #pragma unroll
    for (int r = 0; r < 16; ++r) kZero[r] = 0.f;

    // ---- c projection: c_proj[o] = dot(c[b], Wproj[j][o]) + bproj ----
    float cacc0, cacc1, cacc2, cacc3;
    {
        const float* cb  = c + (size_t)b*128;
        const float* wpj = Wproj + (size_t)j*4*128;
        float cl = cb[lane], chv = cb[lane + 64];
        cacc0 = cl*wpj[0*128+lane] + chv*wpj[0*128+lane+64];
        cacc1 = cl*wpj[1*128+lane] + chv*wpj[1*128+lane+64];
        cacc2 = cl*wpj[2*128+lane] + chv*wpj[2*128+lane+64];
        cacc3 = cl*wpj[3*128+lane] + chv*wpj[3*128+lane+64];
        #pragma unroll
        for (int off = 32; off >= 1; off >>= 1) {
            cacc0 += __shfl_xor(cacc0, off, 64);
            cacc1 += __shfl_xor(cacc1, off, 64);
            cacc2 += __shfl_xor(cacc2, off, 64);
            cacc3 += __shfl_xor(cacc3, off, 64);
        }
        cacc0 += bproj[j*4+0]; cacc1 += bproj[j*4+1];
        cacc2 += bproj[j*4+2]; cacc3 += bproj[j*4+3];
    }
    const float c0v = (lane < 32) ? cacc0 : 0.f;
    unsigned wc2h = pack2(cacc1, cacc2);
    unsigned wc3h = pack2(cacc3, 1.0f);   // k6=c3, k7=1.0 (bias slot)
    if (lane >= 32) { wc2h = 0; wc3h = 0; }
    const float bo = bout[j];

    // ---- main loop over 128-column trips (4 x 32-col chains) ----
    const float* pb0 = p + ((size_t)(b*(NJ*3) + j*3 + 0))*TLEN;
    const float* pb1 = pb0 + TLEN;
    const float* pb2 = pb1 + TLEN;
    float* ob = out + ((size_t)(b*NJ + j))*TLEN;

    const int w0idx = sub*4 + (tid >> 6);

    auto loadP = [&](int itx)->P12 {
        P12 r;
        #pragma unroll
        for (int q = 0; q < 12; ++q) r.v[q] = 0.f;
        if (itx < NIT128 && lane < 32) {
            #pragma unroll
            for (int k = 0; k < 4; ++k) {
                int t = itx*128 + 32*k + lane;
                t = t < TLEN ? t : TLEN-1;
                r.v[3*k+0] = pb0[t];
                r.v[3*k+1] = pb1[t];
                r.v[3*k+2] = pb2[t];
            }
        }
        return r;
    };

    P12 a = loadP(w0idx);

    for (int it = w0idx; it < NIT128; it += NWPB) {
        P12 n = loadP(it + NWPB);   // prefetch next trip

        // 4 input fragments (bf16 hi only; wplo covers weight+bias rounding)
        FragU f[4];
        #pragma unroll
        for (int k = 0; k < 4; ++k) {
            f[k].u[0] = pack2(a.v[3*k+0], a.v[3*k+1]);
            f[k].u[1] = pack2(a.v[3*k+2], c0v);
            f[k].u[2] = wc2h;
            f[k].u[3] = wc3h;
        }

        f32x16 acc[4];
        #pragma unroll
        for (int k = 0; k < 4; ++k) acc[k] = mfma(wphi, f[k], kZero);
        #pragma unroll
        for (int k = 0; k < 4; ++k) acc[k] = mfma(wplo, f[k], acc[k]);

        #pragma unroll
        for (int L = 0; L < 3; ++L) {
            // data-independent bias surface, shared by all 4 chains
            f32x16 bAcc = mfma(mk1(biasA[L]), mk1(ones2), kZero);
            FragU p0[4], p1[4];
            #pragma unroll
            for (int k = 0; k < 4; ++k) relu_pack(acc[k], p0[k], p1[k]);
            #pragma unroll
            for (int k = 0; k < 4; ++k) acc[k] = mfma(whi[L][0], p0[k], bAcc);
            #pragma unroll
            for (int k = 0; k < 4; ++k) acc[k] = mfma(whi[L][1], p1[k], acc[k]);
        }

        // output layer: relu_pack + broadcast-wo MFMA (D[any reg] = dot)
        f32x16 o[4];
        {
            FragU q0[4], q1[4];
            #pragma unroll
            for (int k = 0; k < 4; ++k) relu_pack(acc[k], q0[k], q1[k]);
            #pragma unroll
            for (int k = 0; k < 4; ++k) o[k] = mfma(woF[0], q0[k], kZero);
            #pragma unroll
            for (int k = 0; k < 4; ++k) o[k] = mfma(woF[1], q1[k], o[k]);
        }

        int t1 = it*128 + lane;
        if (t1 < TLEN) ob[t1] = ((lane < 32) ? o[0][0] : o[1][0]) + bo;
        int t2 = t1 + 64;
        if (t2 < TLEN) ob[t2] = ((lane < 32) ? o[2][0] : o[3][0]) + bo;

        a = n;
    }
}

extern "C" void kernel_launch(void* const* d_in, const int* in_sizes, int n_in,
                              void* d_out, int out_size, void* d_ws, size_t ws_size,
                              hipStream_t stream) {
    const float* p     = (const float*)d_in[0];
    // d_in[1] = z (unused by reference)
    const float* c     = (const float*)d_in[2];
    const float* Wproj = (const float*)d_in[3];
    const float* bproj = (const float*)d_in[4];
    const float* Wp    = (const float*)d_in[5];
    const float* bp    = (const float*)d_in[6];
    const float* W0    = (const float*)d_in[7];
    const float* b0    = (const float*)d_in[8];
    const float* W1    = (const float*)d_in[9];
    const float* b1    = (const float*)d_in[10];
    const float* W2    = (const float*)d_in[11];
    const float* b2    = (const float*)d_in[12];
    const float* Wout  = (const float*)d_in[13];
    const float* bout  = (const float*)d_in[14];
    float* out = (float*)d_out;

    dim3 grid(NB*NJ*CHUNKS), block(256);
    ptf_decoder_kernel<<<grid, block, 0, stream>>>(
        p, c, Wproj, bproj, Wp, bp, W0, b0, W1, b1, W2, b2, Wout, bout, out);
}

// Round 9
// 35.969 us; speedup vs baseline: 1.1137x; 1.1137x over previous
//
#include <hip/hip_runtime.h>
#include <hip/hip_bf16.h>

#define NJ 24
#define TLEN 25000
#define NB 4
#define CHUNKS 20
#define NWPB (CHUNKS*4)           // waves per (b,j) = 80
#define NITERS ((TLEN+63)/64)     // 391

typedef short short8 __attribute__((ext_vector_type(8)));
typedef short s16x2 __attribute__((ext_vector_type(2)));
typedef float f32x16 __attribute__((ext_vector_type(16)));

union FragU { unsigned u[4]; short8 s; };

// Fast f32x2 -> packed bf16x2, round-half-up: (bits + 0x8000) then take hi16
// of each via one v_perm_b32. 3 VALU ops. Differs from RTNE only at exact
// half-ulp ties; cannot produce NaN/Inf from finite inputs. NOTE: do NOT use
// inline-asm v_cvt_pk_bf16_f32 — it NaN'd on this toolchain (R5).
__device__ __forceinline__ unsigned pack2(float a, float b){
    unsigned ua = __float_as_uint(a) + 0x8000u;
    unsigned ub = __float_as_uint(b) + 0x8000u;
    return __builtin_amdgcn_perm(ub, ua, 0x07060302u);
}
__device__ __forceinline__ float bflo(unsigned u){
    union { unsigned v; float f; } t; t.v = u << 16; return t.f;
}

// packed bf16 relu: bf16 bit patterns compare correctly as signed i16;
// max_i16(x, 0) maps any negative bf16 to +0.0 and keeps positives.
__device__ __forceinline__ unsigned pkrelu(unsigned x){
    union { unsigned u; s16x2 v; } a, r;
    a.u = x;
    s16x2 z; z[0] = 0; z[1] = 0;
    r.v = __builtin_elementwise_max(a.v, z);
    return r.u;
}

__device__ __forceinline__ f32x16 mfma(const FragU &a, const FragU &b, f32x16 c){
    return __builtin_amdgcn_mfma_f32_32x32x16_bf16(a.s, b.s, c, 0, 0, 0);
}

__device__ __forceinline__ FragU mk1(unsigned w){
    FragU f; f.u[0] = w; f.u[1] = 0; f.u[2] = 0; f.u[3] = 0; return f;
}

// round-to-bf16 then packed relu (== relu then round); zero-shuffle layer
// chaining: channel labels of next layer are pi-permuted so regs 0..7 -> frag
// k0, 8..15 -> frag k1, compensated in the weight gather below.
__device__ __forceinline__ void relu_pack(const f32x16 &acc, FragU &k0, FragU &k1){
    unsigned w[8];
    #pragma unroll
    for (int i = 0; i < 8; ++i) w[i] = pkrelu(pack2(acc[2*i], acc[2*i+1]));
    k0.u[0]=w[0]; k0.u[1]=w[1]; k0.u[2]=w[2]; k0.u[3]=w[3];
    k1.u[0]=w[4]; k1.u[1]=w[5]; k1.u[2]=w[6]; k1.u[3]=w[7];
}

// launch_bounds(256,2): DO NOT raise the 2nd arg — (256,4) caps the unified
// VGPR/AGPR budget at 128/wave, regalloc split 64+64 and spilled (R2: FETCH
// 303MB / WRITE 184MB scratch traffic, 150us).
// R9: CHUNKS 20 (block-count lever — the only consistently positive signal
// R1..R8) + drop first-layer lo-weight correction (chain 10->9 MFMA,
// -2 MFMA/trip, -4 regs; absmax margin 2.2x absorbs it).
__global__ __launch_bounds__(256, 2) void ptf_decoder_kernel(
    const float* __restrict__ p,    const float* __restrict__ c,
    const float* __restrict__ Wproj,const float* __restrict__ bproj,
    const float* __restrict__ Wp,   const float* __restrict__ bp,
    const float* __restrict__ W0,   const float* __restrict__ b0,
    const float* __restrict__ W1,   const float* __restrict__ b1,
    const float* __restrict__ W2,   const float* __restrict__ b2,
    const float* __restrict__ Wout, const float* __restrict__ bout,
    float* __restrict__ out)
{
    __shared__ __align__(16) float ldsW[3][32][36];  // padded: 4-way max on b128 gathers
    __shared__ __align__(16) float ldsWp[32][8];
    __shared__ __align__(16) float ldsB[3][32];
    __shared__ __align__(16) float ldsWo[32];

    const int tid = threadIdx.x;
    const int bj  = blockIdx.x % (NB*NJ);
    const int sub = blockIdx.x / (NB*NJ);
    const int b   = bj / NJ;
    const int j   = bj % NJ;

    // ---- stage this joint's weights into LDS (coalesced) ----
    {
        const float* Wl[3] = {W0, W1, W2};
        #pragma unroll
        for (int L = 0; L < 3; ++L) {
            int row = tid >> 3, c4 = tid & 7;           // 256 threads = 32 rows x 8 float4
            float4 v = *reinterpret_cast<const float4*>(Wl[L] + ((size_t)(j*32 + row))*32 + c4*4);
            *reinterpret_cast<float4*>(&ldsW[L][row][c4*4]) = v;
        }
        {
            int row = tid >> 3, i8 = tid & 7;
            // col 7 carries b_p (first-layer bias rides k=7 with input 1.0)
            ldsWp[row][i8] = (i8 < 7) ? Wp[((size_t)(j*32 + row))*7 + i8]
                                      : bp[j*32 + row];
        }
        if      (tid < 32)  ldsB[0][tid]      = b0[j*32 + tid];
        else if (tid < 64)  ldsB[1][tid-32]   = b1[j*32 + tid-32];
        else if (tid < 96)  ldsB[2][tid-64]   = b2[j*32 + tid-64];
        else if (tid < 128) ldsWo[tid-96]     = Wout[j*32 + tid-96];
    }
    __syncthreads();

    const int lane = tid & 63;
    const int row  = lane & 31;
    const int h    = lane >> 5;

    // ---- per-lane weight fragments (bf16 hi only), pi-permuted k labels ----
    FragU whi[3][2];
    #pragma unroll
    for (int L = 0; L < 3; ++L) {
        #pragma unroll
        for (int kh = 0; kh < 2; ++kh) {
            const int g  = kh*2 + h;                 // k-group
            const int cA = (g >> 1)*4 + (g & 1);     // chunk pairs {0,2},{1,3},{4,6},{5,7}
            const float* base = &ldsW[L][row][0];
            float4 x = *reinterpret_cast<const float4*>(base + cA*4);
            float4 y = *reinterpret_cast<const float4*>(base + (cA+2)*4);
            whi[L][kh].u[0] = pack2(x.x, x.y);
            whi[L][kh].u[1] = pack2(x.z, x.w);
            whi[L][kh].u[2] = pack2(y.x, y.y);
            whi[L][kh].u[3] = pack2(y.z, y.w);
        }
    }
    // output layer as MFMA: wo broadcast to all 32 rows, same pi-compensated
    // column gather as whi -> every D reg holds the full 1x32 dot.
    FragU woF[2];
    #pragma unroll
    for (int kh = 0; kh < 2; ++kh) {
        const int g  = kh*2 + h;
        const int cA = (g >> 1)*4 + (g & 1);
        float4 x = *reinterpret_cast<const float4*>(&ldsWo[cA*4]);
        float4 y = *reinterpret_cast<const float4*>(&ldsWo[(cA+2)*4]);
        woF[kh].u[0] = pack2(x.x, x.y);
        woF[kh].u[1] = pack2(x.z, x.w);
        woF[kh].u[2] = pack2(y.x, y.y);
        woF[kh].u[3] = pack2(y.z, y.w);
    }
    // first layer: bf16 hi only as well (R9: wplo dropped — margin absorbs it)
    FragU wphi;
    {
        float4 x = make_float4(0,0,0,0), y = make_float4(0,0,0,0);
        if (lane < 32) {
            x = *reinterpret_cast<const float4*>(&ldsWp[row][0]);
            y = *reinterpret_cast<const float4*>(&ldsWp[row][4]);
        }
        wphi.u[0] = pack2(x.x, x.y);
        wphi.u[1] = pack2(x.z, x.w);
        wphi.u[2] = pack2(y.x, y.y);
        wphi.u[3] = pack2(y.z, y.w);
    }

    // ---- hidden-layer biases as 1-reg A-fragments: k0=hi(b), k1=lo(b) ----
    unsigned biasA[3];
    #pragma unroll
    for (int L = 0; L < 3; ++L) {
        float bl = (h == 0) ? ldsB[L][row] : 0.f;
        unsigned t = pack2(bl, 0.f);
        float res = bl - bflo(t);
        biasA[L] = (h == 0) ? pack2(bl, res) : 0u;
    }
    const unsigned ones2 = (h == 0) ? 0x3f803f80u : 0u;   // {1.0bf16, 1.0bf16}

    // shared zero accumulator C (read-only)
    f32x16 kZero;
    #pragma unroll
    for (int r = 0; r < 16; ++r) kZero[r] = 0.f;

    // ---- c projection: c_proj[o] = dot(c[b], Wproj[j][o]) + bproj ----
    float cacc0, cacc1, cacc2, cacc3;
    {
        const float* cb  = c + (size_t)b*128;
        const float* wpj = Wproj + (size_t)j*4*128;
        float cl = cb[lane], chv = cb[lane + 64];
        cacc0 = cl*wpj[0*128+lane] + chv*wpj[0*128+lane+64];
        cacc1 = cl*wpj[1*128+lane] + chv*wpj[1*128+lane+64];
        cacc2 = cl*wpj[2*128+lane] + chv*wpj[2*128+lane+64];
        cacc3 = cl*wpj[3*128+lane] + chv*wpj[3*128+lane+64];
        #pragma unroll
        for (int off = 32; off >= 1; off >>= 1) {
            cacc0 += __shfl_xor(cacc0, off, 64);
            cacc1 += __shfl_xor(cacc1, off, 64);
            cacc2 += __shfl_xor(cacc2, off, 64);
            cacc3 += __shfl_xor(cacc3, off, 64);
        }
        cacc0 += bproj[j*4+0]; cacc1 += bproj[j*4+1];
        cacc2 += bproj[j*4+2]; cacc3 += bproj[j*4+3];
    }
    const float c0v = (lane < 32) ? cacc0 : 0.f;
    unsigned wc2h = pack2(cacc1, cacc2);
    unsigned wc3h = pack2(cacc3, 1.0f);   // k6=c3, k7=1.0 (bias slot)
    if (lane >= 32) { wc2h = 0; wc3h = 0; }
    const float bo = bout[j];

    // ---- main loop over 64-column tiles ----
    const float* pb0 = p + ((size_t)(b*(NJ*3) + j*3 + 0))*TLEN;
    const float* pb1 = pb0 + TLEN;
    const float* pb2 = pb1 + TLEN;
    float* ob = out + ((size_t)(b*NJ + j))*TLEN;

    const int w0idx = sub*4 + (tid >> 6);

    auto loadP = [&](int itx, float&x0,float&x1,float&x2,float&x3,float&x4,float&x5){
        x0=0.f;x1=0.f;x2=0.f;x3=0.f;x4=0.f;x5=0.f;
        if (itx < NITERS && lane < 32) {
            int tA = itx*64 + lane;
            int tB = tA + 32;
            tA = tA < TLEN ? tA : TLEN-1;
            tB = tB < TLEN ? tB : TLEN-1;
            x0 = pb0[tA]; x1 = pb1[tA]; x2 = pb2[tA];
            x3 = pb0[tB]; x4 = pb1[tB]; x5 = pb2[tB];
        }
    };

    float a0,a1,a2,a3,a4,a5;
    loadP(w0idx, a0,a1,a2,a3,a4,a5);

    for (int it = w0idx; it < NITERS; it += NWPB) {
        float n0,n1,n2,n3,n4,n5;
        loadP(it + NWPB, n0,n1,n2,n3,n4,n5);   // prefetch next tile

        // input fragments (bf16 hi only)
        FragU fAh, fBh;
        fAh.u[0] = pack2(a0, a1);  fAh.u[1] = pack2(a2, c0v);
        fBh.u[0] = pack2(a3, a4);  fBh.u[1] = pack2(a5, c0v);
        fAh.u[2]=wc2h; fAh.u[3]=wc3h;
        fBh.u[2]=wc2h; fBh.u[3]=wc3h;

        f32x16 accA, accB;
        accA = mfma(wphi, fAh, kZero);
        accB = mfma(wphi, fBh, kZero);

        #pragma unroll
        for (int L = 0; L < 3; ++L) {
            // data-independent bias surface (same for A and B chains);
            // issued before relu_pack so it overlaps the VALU packing.
            f32x16 bAcc = mfma(mk1(biasA[L]), mk1(ones2), kZero);
            FragU pA0, pA1, pB0, pB1;
            relu_pack(accA, pA0, pA1);
            relu_pack(accB, pB0, pB1);
            accA = mfma(whi[L][0], pA0, bAcc);
            accB = mfma(whi[L][0], pB0, bAcc);
            accA = mfma(whi[L][1], pA1, accA);
            accB = mfma(whi[L][1], pB1, accB);
        }

        // output layer: relu_pack + broadcast-wo MFMA (D[any reg] = dot)
        FragU qA0, qA1, qB0, qB1;
        relu_pack(accA, qA0, qA1);
        relu_pack(accB, qB0, qB1);
        f32x16 oA = mfma(woF[0], qA0, kZero);
        f32x16 oB = mfma(woF[0], qB0, kZero);
        oA = mfma(woF[1], qA1, oA);
        oB = mfma(woF[1], qB1, oB);

        int t = it*64 + lane;
        if (t < TLEN) ob[t] = ((lane < 32) ? oA[0] : oB[0]) + bo;

        a0=n0; a1=n1; a2=n2; a3=n3; a4=n4; a5=n5;
    }
}

extern "C" void kernel_launch(void* const* d_in, const int* in_sizes, int n_in,
                              void* d_out, int out_size, void* d_ws, size_t ws_size,
                              hipStream_t stream) {
    const float* p     = (const float*)d_in[0];
    // d_in[1] = z (unused by reference)
    const float* c     = (const float*)d_in[2];
    const float* Wproj = (const float*)d_in[3];
    const float* bproj = (const float*)d_in[4];
    const float* Wp    = (const float*)d_in[5];
    const float* bp    = (const float*)d_in[6];
    const float* W0    = (const float*)d_in[7];
    const float* b0    = (const float*)d_in[8];
    const float* W1    = (const float*)d_in[9];
    const float* b1    = (const float*)d_in[10];
    const float* W2    = (const float*)d_in[11];
    const float* b2    = (const float*)d_in[12];
    const float* Wout  = (const float*)d_in[13];
    const float* bout  = (const float*)d_in[14];
    float* out = (float*)d_out;

    dim3 grid(NB*NJ*CHUNKS), block(256);
    ptf_decoder_kernel<<<grid, block, 0, stream>>>(
        p, c, Wproj, bproj, Wp, bp, W0, b0, W1, b1, W2, b2, Wout, bout, out);
}